// Round 7
// baseline (777.360 us; speedup 1.0000x reference)
//
#include <hip/hip_runtime.h>
#include <math.h>

#define BB 32
#define NN 16000
#define CC 128
#define LL 512
#define OO 35
#define TT 100
#define BTO (BB * TT * OO)   // 112000
#define FSR 16000.0

// conv recursion segmentation
#define SEG 640              // 4 IHC windows per segment
#define NSEG 25
#define SPAN 1153            // audio span per segment: [n0-256, n0+896]

// ws layout (bytes). cur_d overlaps Wt/params (dead by the time an_cur runs).
#define WT_OFF   0            // [512][128][2] double = 1 MB
#define PAR_OFF  0x100000     // [128][16] double = 16 KB
#define CUR_OFF  0            // [3200][128] double = 3.28 MB (written after conv)
#define XT_OFF   0x350000     // [3200][128] float = 1.64 MB

// ---------------- Gammatone tables: Wt[l][c] = rho_c^l, per-channel params ----------------
__global__ __launch_bounds__(512) void gt_tables(double* __restrict__ Wt,
                                                 double* __restrict__ par) {
    const int c = blockIdx.x;      // 0..127
    const int l = threadIdx.x;     // 0..511
    const double TWO_PI = 6.283185307179586476925287;
    const double e_lo = 21.4 * log10(4.37 * 100.0 / 1000.0 + 1.0);
    const double e_hi = 21.4 * log10(4.37 * 8000.0 / 1000.0 + 1.0);
    const double step = (e_hi - e_lo) / 127.0;
    const double e = (c == 127) ? e_hi : e_lo + c * step;
    const double cf = (pow(10.0, e / 21.4) - 1.0) * 1000.0 / 4.37;
    const double bw = 1.019 * 24.7 * (4.37 * cf / 1000.0 + 1.0);

    const double t = (double)l / FSR;
    const double env = exp(-TWO_PI * bw * t);
    const double ang = TWO_PI * cf * t;
    const double wr = env * cos(ang);
    const double wi = env * sin(ang);
    Wt[(l * CC + c) * 2 + 0] = wr;
    Wt[(l * CC + c) * 2 + 1] = wi;

    __shared__ double red[512];
    const double l3 = (double)l * (double)l * (double)l;
    const double q = l3 * wr;
    red[l] = q * q;
    __syncthreads();
    for (int s = 256; s > 0; s >>= 1) {
        if (l < s) red[l] += red[l + s];
        __syncthreads();
    }
    if (l == 0) {
        double* p = par + c * 16;
        const double a1 = TWO_PI * bw / FSR, th1 = TWO_PI * cf / FSR;
        const double e1 = exp(-a1);
        p[0] = e1 * cos(th1);              // rho.re
        p[1] = e1 * sin(th1);              // rho.im
        const double aL = TWO_PI * bw * (512.0 / FSR), thL = TWO_PI * cf * (512.0 / FSR);
        const double eL = exp(-aL);
        const double pr = eL * cos(thL), pim = eL * sin(thL);   // rho^512
        p[2] = pr;              p[3] = pim;               // C0
        p[4] = 512.0 * pr;      p[5] = 512.0 * pim;       // C1
        p[6] = 130816.0 * pr;   p[7] = 130816.0 * pim;    // C2
        p[8] = 22238720.0 * pr; p[9] = 22238720.0 * pim;  // C3
        p[10] = 1.0 / sqrt(red[0]);
    }
}

// ---------------- Conv via exact FIR recursion + ReLU + IHC window mean ----------------
__global__ __launch_bounds__(128) void conv_rec(
    const float* __restrict__ audio,   // [B,N]
    const double* __restrict__ Wt,     // [512][128][2]
    const double* __restrict__ par,    // [128][16]
    float* __restrict__ xt)            // [B,T,C]
{
    const int blk = blockIdx.x;
    const int b = blk / NSEG;
    const int seg = blk % NSEG;
    const int n0 = seg * SEG;
    const int c = threadIdx.x;

    __shared__ float alds[SPAN];
    for (int i = c; i < SPAN; i += 128) {
        const int g = n0 - 256 + i;
        alds[i] = (g >= 0 && g < NN) ? audio[b * NN + g] : 0.0f;
    }
    __syncthreads();

    const double* p = par + c * 16;
    const double rr = p[0], ri = p[1];
    const double cr0 = p[2], ci0 = p[3], cr1 = p[4], ci1 = p[5];
    const double cr2 = p[6], ci2 = p[7], cr3 = p[8], ci3 = p[9];
    const double scale = p[10];

    double d0r = 0, d0i = 0, d1r = 0, d1i = 0, d2r = 0, d2i = 0, d3r = 0, d3i = 0;
    #pragma unroll 4
    for (int l = 0; l < 512; ++l) {
        const double wr = Wt[(l * CC + c) * 2 + 0];
        const double wi = Wt[(l * CC + c) * 2 + 1];
        const double av = (double)alds[SEG + 1 + l];
        const double bl = (double)l;
        const double b2 = bl * (bl - 1.0) * 0.5;
        const double b3 = b2 * (bl - 2.0) * (1.0 / 3.0);
        d0r = fma(wr, av, d0r);              d0i = fma(wi, av, d0i);
        const double t1 = av * bl;
        d1r = fma(wr, t1, d1r);              d1i = fma(wi, t1, d1i);
        const double t2 = av * b2;
        d2r = fma(wr, t2, d2r);              d2i = fma(wi, t2, d2i);
        const double t3 = av * b3;
        d3r = fma(wr, t3, d3r);              d3i = fma(wi, t3, d3i);
    }

    double wsum = 0.0;
    int widx = (b * TT + seg * 4 + 3) * CC + c;
    int cnt = 0;
    #pragma unroll 2
    for (int m = 0; m < SEG; ++m) {
        const int li = SEG - m;
        const double ain  = (double)alds[li];
        const double aout = (double)alds[li + 512];
        const double t3r = d3r + d2r, t3i = d3i + d2i;
        const double t2r = d2r + d1r, t2i = d2i + d1i;
        const double t1r = d1r + d0r, t1i = d1i + d0i;
        d3r = fma(t3r, rr, fma(t3i, -ri, -cr3 * aout));
        d3i = fma(t3r, ri, fma(t3i,  rr, -ci3 * aout));
        d2r = fma(t2r, rr, fma(t2i, -ri, -cr2 * aout));
        d2i = fma(t2r, ri, fma(t2i,  rr, -ci2 * aout));
        d1r = fma(t1r, rr, fma(t1i, -ri, -cr1 * aout));
        d1i = fma(t1r, ri, fma(t1i,  rr, -ci1 * aout));
        const double o0r = fma(d0r, rr, fma(d0i, -ri, fma(-cr0, aout, ain)));
        const double o0i = fma(d0r, ri, fma(d0i,  rr, -ci0 * aout));
        d0r = o0r; d0i = o0i;
        const double yv = scale * fma(6.0, d2r + d3r, d1r);
        float yf = (float)yv;
        yf = yf > 0.0f ? yf : 0.0f;
        wsum += (double)yf;
        if (++cnt == 160) {
            xt[widx] = (float)(wsum / 160.0);
            widx -= CC;
            wsum = 0.0;
            cnt = 0;
        }
    }
}

// ---------------- AN current precompute (fp64): cur = xt @ W_an^T + b_an ----------------
__global__ __launch_bounds__(128) void an_cur_kernel(
    const float* __restrict__ xt, const float* __restrict__ W_an,
    const float* __restrict__ b_an, double* __restrict__ cur_d)
{
    __shared__ float xr[CC];
    const int row = blockIdx.x;          // b*T + t
    const int c = threadIdx.x;
    xr[c] = xt[row * CC + c];
    __syncthreads();
    const float* wr = W_an + c * CC;
    double acc = (double)b_an[c];
    #pragma unroll
    for (int k = 0; k < CC; k += 4) {
        float4 w4 = *reinterpret_cast<const float4*>(wr + k);
        acc += (double)w4.x * (double)xr[k]
             + (double)w4.y * (double)xr[k+1]
             + (double)w4.z * (double)xr[k+2]
             + (double)w4.w * (double)xr[k+3];
    }
    cur_d[row * CC + c] = acc;
}

// ---------------- SNN scan: one block (128 threads, 2 waves) per batch ----------------
// Lane c owns channel c. Band weights f64 in VGPRs; spikes f64 in LDS
// (lane-consecutive b64 reads). IC weights transposed double2 in LDS
// (lane-consecutive b128 reads + b128 broadcast of spike pairs).
#define R1 8
#define W1 17
#define R2 16
#define W2 33
#define R3 24
#define W3 49
#define SPW 32                // spike pad (f64 elems) each side; row = 192
#define CHK 5

__global__ __launch_bounds__(128) void snn_kernel(
    const double* __restrict__ cur_an, // [B,T,C] fp64 AN currents
    const float* __restrict__ W_b, const float* __restrict__ W_m, const float* __restrict__ W_n,
    const float* __restrict__ W_ic, const float* __restrict__ b_ic,
    const float* __restrict__ W_ac, const float* __restrict__ b_ac,
    float* __restrict__ out)           // [2,B,T,O]
{
    __shared__ double2 wicT2[64 * CC];              // [k2][c] = (W_ic[c][2k2], W_ic[c][2k2+1]) 128KB
    __shared__ float   wacT[CC * 36];               // [k*36+o] = W_ac[o][k]  18KB
    __shared__ double  spkf[4 * 192];               // A,B,M,N spike rows, padded
    __shared__ __align__(16) double sic[CC];
    __shared__ double  part[72];

    const int b = blockIdx.x;
    const int tid = threadIdx.x;   // 0..127 == channel c
    const int c = tid;

    // ---- stage IC weights transposed (double2 along k) ----
    {
        const float2* src = reinterpret_cast<const float2*>(W_ic + c * CC);
        #pragma unroll 8
        for (int k2 = 0; k2 < 64; ++k2) {
            float2 v = src[k2];
            wicT2[(k2 << 7) + c] = make_double2((double)v.x, (double)v.y);
        }
    }
    // ---- stage AC weights transposed (f32) ----
    for (int i = tid; i < OO * CC; i += 128) {
        const int o = i >> 7, k = i & 127;
        wacT[k * 36 + o] = W_ac[o * CC + k];
    }
    // ---- zero spike rows incl. pads ----
    for (int i = tid; i < 4 * 192; i += 128) spkf[i] = 0.0;

    // ---- band weights into f64 registers (OOB = 0) ----
    double w1d[W1], w2d[W2], w3d[W3];
    #pragma unroll
    for (int x = 0; x < W1; ++x) { int k = c - R1 + x; w1d[x] = (k >= 0 && k < CC) ? (double)W_b[c * CC + k] : 0.0; }
    #pragma unroll
    for (int x = 0; x < W2; ++x) { int k = c - R2 + x; w2d[x] = (k >= 0 && k < CC) ? (double)W_m[c * CC + k] : 0.0; }
    #pragma unroll
    for (int x = 0; x < W3; ++x) { int k = c - R3 + x; w3d[x] = (k >= 0 && k < CC) ? (double)W_n[c * CC + k] : 0.0; }

    const double bicd = (double)b_ic[c];
    const double bacd = ((tid & 63) < OO) ? (double)b_ac[tid & 63] : 0.0;
    __syncthreads();

    double m1 = 0, m2 = 0, m3 = 0, m4 = 0, m5 = 0, mac = 0;

    for (int tc = 0; tc < TT; tc += CHK) {
        double curb[CHK];
        #pragma unroll
        for (int k = 0; k < CHK; ++k)
            curb[k] = cur_an[(b * TT + tc + k) * CC + c];

        #pragma unroll
        for (int u = 0; u < CHK; ++u) {
            const int t = tc + u;
            // ---- AN (th 0.5) ----
            {
                double mem = 0.9 * m1 + curb[u];
                double d = mem - 0.5; bool s = d > 0.0; m1 = s ? d : mem;
                spkf[0 * 192 + SPW + c] = s ? 1.0 : 0.0;
            }
            __syncthreads();
            // ---- Bushy (std=1) ----
            {
                const double* sp = &spkf[0 * 192 + SPW + c - R1];
                double a0 = 0, a1 = 0, a2 = 0, a3 = 0;
                #pragma unroll
                for (int x = 0; x < W1; x += 4) {
                    a0 = fma(w1d[x], sp[x], a0);
                    if (x + 1 < W1) a1 = fma(w1d[x + 1], sp[x + 1], a1);
                    if (x + 2 < W1) a2 = fma(w1d[x + 2], sp[x + 2], a2);
                    if (x + 3 < W1) a3 = fma(w1d[x + 3], sp[x + 3], a3);
                }
                double mem = 0.9 * m2 + ((a0 + a1) + (a2 + a3));
                double d = mem - 1.0; bool s = d > 0.0; m2 = s ? d : mem;
                spkf[1 * 192 + SPW + c] = s ? 1.0 : 0.0;
            }
            __syncthreads();
            // ---- Stellate M (std=2) ----
            {
                const double* sp = &spkf[1 * 192 + SPW + c - R2];
                double a0 = 0, a1 = 0, a2 = 0, a3 = 0;
                #pragma unroll
                for (int x = 0; x < W2; x += 4) {
                    a0 = fma(w2d[x], sp[x], a0);
                    if (x + 1 < W2) a1 = fma(w2d[x + 1], sp[x + 1], a1);
                    if (x + 2 < W2) a2 = fma(w2d[x + 2], sp[x + 2], a2);
                    if (x + 3 < W2) a3 = fma(w2d[x + 3], sp[x + 3], a3);
                }
                double mem = 0.9 * m3 + ((a0 + a1) + (a2 + a3));
                double d = mem - 1.0; bool s = d > 0.0; m3 = s ? d : mem;
                spkf[2 * 192 + SPW + c] = s ? 1.0 : 0.0;
            }
            __syncthreads();
            // ---- Stellate N (std=3) ----
            {
                const double* sp = &spkf[2 * 192 + SPW + c - R3];
                double a0 = 0, a1 = 0, a2 = 0, a3 = 0;
                #pragma unroll
                for (int x = 0; x < W3; x += 4) {
                    a0 = fma(w3d[x], sp[x], a0);
                    if (x + 1 < W3) a1 = fma(w3d[x + 1], sp[x + 1], a1);
                    if (x + 2 < W3) a2 = fma(w3d[x + 2], sp[x + 2], a2);
                    if (x + 3 < W3) a3 = fma(w3d[x + 3], sp[x + 3], a3);
                }
                double mem = 0.9 * m4 + ((a0 + a1) + (a2 + a3));
                double d = mem - 1.0; bool s = d > 0.0; m4 = s ? d : mem;
                spkf[3 * 192 + SPW + c] = s ? 1.0 : 0.0;
            }
            __syncthreads();
            // ---- IC dense 128x128: lane-consecutive b128 weights + b128 spike broadcast ----
            {
                double a0 = bicd, a1 = 0, a2 = 0, a3 = 0;
                const double2* wp = &wicT2[c];
                const double* snp = &spkf[3 * 192 + SPW];
                #pragma unroll 16
                for (int k2 = 0; k2 < 64; k2 += 2) {
                    double2 wv0 = wp[k2 << 7];
                    double2 sv0 = *reinterpret_cast<const double2*>(&snp[2 * k2]);
                    double2 wv1 = wp[(k2 + 1) << 7];
                    double2 sv1 = *reinterpret_cast<const double2*>(&snp[2 * k2 + 2]);
                    a0 = fma(wv0.x, sv0.x, a0);
                    a1 = fma(wv0.y, sv0.y, a1);
                    a2 = fma(wv1.x, sv1.x, a2);
                    a3 = fma(wv1.y, sv1.y, a3);
                }
                double mem = 0.9 * m5 + ((a0 + a1) + (a2 + a3));
                double d = mem - 1.0; bool s = d > 0.0; m5 = s ? d : mem;
                sic[c] = s ? 1.0 : 0.0;
            }
            __syncthreads();
            // ---- AC 35x128: split across waves (h = tid>>6), 64 taps each ----
            {
                const int o = tid & 63, h = tid >> 6;
                if (o < OO) {
                    const int kb = h << 6;
                    double a0 = 0, a1 = 0, a2 = 0, a3 = 0;
                    #pragma unroll 8
                    for (int k2 = 0; k2 < 32; k2 += 2) {
                        double2 sv0 = *reinterpret_cast<const double2*>(&sic[kb + 2 * k2]);
                        double2 sv1 = *reinterpret_cast<const double2*>(&sic[kb + 2 * k2 + 2]);
                        a0 = fma((double)wacT[(kb + 2 * k2) * 36 + o],     sv0.x, a0);
                        a1 = fma((double)wacT[(kb + 2 * k2 + 1) * 36 + o], sv0.y, a1);
                        a2 = fma((double)wacT[(kb + 2 * k2 + 2) * 36 + o], sv1.x, a2);
                        a3 = fma((double)wacT[(kb + 2 * k2 + 3) * 36 + o], sv1.y, a3);
                    }
                    part[h * 36 + o] = (a0 + a1) + (a2 + a3);
                }
            }
            __syncthreads();
            if (tid < OO) {
                double acc = part[tid] + part[36 + tid] + bacd;
                double mem = 0.9 * mac + acc;
                double d = mem - 1.0; bool s = d > 0.0;
                mac = s ? d : mem;
                const int idx = (b * TT + t) * OO + tid;
                out[idx] = s ? 1.f : 0.f;
                out[BTO + idx] = (float)mac;
            }
            // no barrier: spkA rewrite is 1 phase + barrier away only for
            // writers; part/sic next writes are >=2 barriers away.
        }
    }
}

extern "C" void kernel_launch(void* const* d_in, const int* in_sizes, int n_in,
                              void* d_out, int out_size, void* d_ws, size_t ws_size,
                              hipStream_t stream) {
    const float* audio = (const float*)d_in[0];
    const float* W_an  = (const float*)d_in[2];
    const float* b_an  = (const float*)d_in[3];
    const float* W_b   = (const float*)d_in[4];
    const float* W_m   = (const float*)d_in[5];
    const float* W_n   = (const float*)d_in[6];
    const float* W_ic  = (const float*)d_in[7];
    const float* b_ic  = (const float*)d_in[8];
    const float* W_ac  = (const float*)d_in[9];
    const float* b_ac  = (const float*)d_in[10];
    // d_in[1] = gt_kernels (rebuilt analytically), d_in[11] = ihc_win (160)

    char* ws = (char*)d_ws;
    double* Wt    = (double*)(ws + WT_OFF);
    double* par   = (double*)(ws + PAR_OFF);
    double* cur_d = (double*)(ws + CUR_OFF);
    float*  xt    = (float*)(ws + XT_OFF);
    float*  out   = (float*)d_out;

    gt_tables<<<dim3(CC), dim3(512), 0, stream>>>(Wt, par);
    conv_rec<<<dim3(BB * NSEG), dim3(128), 0, stream>>>(audio, Wt, par, xt);
    an_cur_kernel<<<dim3(BB * TT), dim3(128), 0, stream>>>(xt, W_an, b_an, cur_d);
    snn_kernel<<<dim3(BB), dim3(128), 0, stream>>>(
        cur_d, W_b, W_m, W_n, W_ic, b_ic, W_ac, b_ac, out);
}

// Round 8
// 574.317 us; speedup vs baseline: 1.3535x; 1.3535x over previous
//
#include <hip/hip_runtime.h>
#include <math.h>

#define BB 32
#define NN 16000
#define CC 128
#define LL 512
#define OO 35
#define TT 100
#define BTO (BB * TT * OO)   // 112000
#define FSR 16000.0

// conv recursion segmentation
#define SEG 640              // 4 IHC windows per segment
#define NSEG 25
#define SPAN 1153            // audio span per segment: [n0-256, n0+896]

// ws layout (bytes). cur_d overlaps Wt/params (dead by the time an_cur runs).
#define WT_OFF   0            // [512][128][2] double = 1 MB
#define PAR_OFF  0x100000     // [128][16] double = 16 KB
#define CUR_OFF  0            // [3200][128] double = 3.28 MB (written after conv)
#define XT_OFF   0x350000     // [3200][128] float = 1.64 MB

// ---------------- Gammatone tables: Wt[l][c] = rho_c^l, per-channel params ----------------
__global__ __launch_bounds__(512) void gt_tables(double* __restrict__ Wt,
                                                 double* __restrict__ par) {
    const int c = blockIdx.x;      // 0..127
    const int l = threadIdx.x;     // 0..511
    const double TWO_PI = 6.283185307179586476925287;
    const double e_lo = 21.4 * log10(4.37 * 100.0 / 1000.0 + 1.0);
    const double e_hi = 21.4 * log10(4.37 * 8000.0 / 1000.0 + 1.0);
    const double step = (e_hi - e_lo) / 127.0;
    const double e = (c == 127) ? e_hi : e_lo + c * step;
    const double cf = (pow(10.0, e / 21.4) - 1.0) * 1000.0 / 4.37;
    const double bw = 1.019 * 24.7 * (4.37 * cf / 1000.0 + 1.0);

    const double t = (double)l / FSR;
    const double env = exp(-TWO_PI * bw * t);
    const double ang = TWO_PI * cf * t;
    const double wr = env * cos(ang);
    const double wi = env * sin(ang);
    Wt[(l * CC + c) * 2 + 0] = wr;
    Wt[(l * CC + c) * 2 + 1] = wi;

    __shared__ double red[512];
    const double l3 = (double)l * (double)l * (double)l;
    const double q = l3 * wr;
    red[l] = q * q;
    __syncthreads();
    for (int s = 256; s > 0; s >>= 1) {
        if (l < s) red[l] += red[l + s];
        __syncthreads();
    }
    if (l == 0) {
        double* p = par + c * 16;
        const double a1 = TWO_PI * bw / FSR, th1 = TWO_PI * cf / FSR;
        const double e1 = exp(-a1);
        p[0] = e1 * cos(th1);              // rho.re
        p[1] = e1 * sin(th1);              // rho.im
        const double aL = TWO_PI * bw * (512.0 / FSR), thL = TWO_PI * cf * (512.0 / FSR);
        const double eL = exp(-aL);
        const double pr = eL * cos(thL), pim = eL * sin(thL);   // rho^512
        p[2] = pr;              p[3] = pim;               // C0
        p[4] = 512.0 * pr;      p[5] = 512.0 * pim;       // C1
        p[6] = 130816.0 * pr;   p[7] = 130816.0 * pim;    // C2
        p[8] = 22238720.0 * pr; p[9] = 22238720.0 * pim;  // C3
        p[10] = 1.0 / sqrt(red[0]);
    }
}

// ---------------- Conv via exact FIR recursion + ReLU + IHC window mean ----------------
__global__ __launch_bounds__(128) void conv_rec(
    const float* __restrict__ audio,   // [B,N]
    const double* __restrict__ Wt,     // [512][128][2]
    const double* __restrict__ par,    // [128][16]
    float* __restrict__ xt)            // [B,T,C]
{
    const int blk = blockIdx.x;
    const int b = blk / NSEG;
    const int seg = blk % NSEG;
    const int n0 = seg * SEG;
    const int c = threadIdx.x;

    __shared__ float alds[SPAN];
    for (int i = c; i < SPAN; i += 128) {
        const int g = n0 - 256 + i;
        alds[i] = (g >= 0 && g < NN) ? audio[b * NN + g] : 0.0f;
    }
    __syncthreads();

    const double* p = par + c * 16;
    const double rr = p[0], ri = p[1];
    const double cr0 = p[2], ci0 = p[3], cr1 = p[4], ci1 = p[5];
    const double cr2 = p[6], ci2 = p[7], cr3 = p[8], ci3 = p[9];
    const double scale = p[10];

    double d0r = 0, d0i = 0, d1r = 0, d1i = 0, d2r = 0, d2i = 0, d3r = 0, d3i = 0;
    #pragma unroll 4
    for (int l = 0; l < 512; ++l) {
        const double wr = Wt[(l * CC + c) * 2 + 0];
        const double wi = Wt[(l * CC + c) * 2 + 1];
        const double av = (double)alds[SEG + 1 + l];
        const double bl = (double)l;
        const double b2 = bl * (bl - 1.0) * 0.5;
        const double b3 = b2 * (bl - 2.0) * (1.0 / 3.0);
        d0r = fma(wr, av, d0r);              d0i = fma(wi, av, d0i);
        const double t1 = av * bl;
        d1r = fma(wr, t1, d1r);              d1i = fma(wi, t1, d1i);
        const double t2 = av * b2;
        d2r = fma(wr, t2, d2r);              d2i = fma(wi, t2, d2i);
        const double t3 = av * b3;
        d3r = fma(wr, t3, d3r);              d3i = fma(wi, t3, d3i);
    }

    double wsum = 0.0;
    int widx = (b * TT + seg * 4 + 3) * CC + c;
    int cnt = 0;
    #pragma unroll 2
    for (int m = 0; m < SEG; ++m) {
        const int li = SEG - m;
        const double ain  = (double)alds[li];
        const double aout = (double)alds[li + 512];
        const double t3r = d3r + d2r, t3i = d3i + d2i;
        const double t2r = d2r + d1r, t2i = d2i + d1i;
        const double t1r = d1r + d0r, t1i = d1i + d0i;
        d3r = fma(t3r, rr, fma(t3i, -ri, -cr3 * aout));
        d3i = fma(t3r, ri, fma(t3i,  rr, -ci3 * aout));
        d2r = fma(t2r, rr, fma(t2i, -ri, -cr2 * aout));
        d2i = fma(t2r, ri, fma(t2i,  rr, -ci2 * aout));
        d1r = fma(t1r, rr, fma(t1i, -ri, -cr1 * aout));
        d1i = fma(t1r, ri, fma(t1i,  rr, -ci1 * aout));
        const double o0r = fma(d0r, rr, fma(d0i, -ri, fma(-cr0, aout, ain)));
        const double o0i = fma(d0r, ri, fma(d0i,  rr, -ci0 * aout));
        d0r = o0r; d0i = o0i;
        const double yv = scale * fma(6.0, d2r + d3r, d1r);
        float yf = (float)yv;
        yf = yf > 0.0f ? yf : 0.0f;
        wsum += (double)yf;
        if (++cnt == 160) {
            xt[widx] = (float)(wsum / 160.0);
            widx -= CC;
            wsum = 0.0;
            cnt = 0;
        }
    }
}

// ---------------- AN current precompute (fp64): cur = xt @ W_an^T + b_an ----------------
__global__ __launch_bounds__(128) void an_cur_kernel(
    const float* __restrict__ xt, const float* __restrict__ W_an,
    const float* __restrict__ b_an, double* __restrict__ cur_d)
{
    __shared__ float xr[CC];
    const int row = blockIdx.x;          // b*T + t
    const int c = threadIdx.x;
    xr[c] = xt[row * CC + c];
    __syncthreads();
    const float* wr = W_an + c * CC;
    double acc = (double)b_an[c];
    #pragma unroll
    for (int k = 0; k < CC; k += 4) {
        float4 w4 = *reinterpret_cast<const float4*>(wr + k);
        acc += (double)w4.x * (double)xr[k]
             + (double)w4.y * (double)xr[k+1]
             + (double)w4.z * (double)xr[k+2]
             + (double)w4.w * (double)xr[k+3];
    }
    cur_d[row * CC + c] = acc;
}

// ---------------- SNN scan: one block (256 threads, 4 waves) per batch ----------------
// R5 structure (passed) with all hot-loop WEIGHT reads moved to VGPRs (f32,
// exact cvt->f64 at use). Spikes stay f64 in LDS; IC/AC spike reads as
// aligned double2. LDS instr/step/wave ~390 -> ~150.
#define R1 8
#define W1 17
#define R2 16
#define W2 33
#define R3 24
#define W3 49
#define SPW 24                // spike pad each side; &spk[SPW] is 16B-aligned
#define CHK 5

__global__ __launch_bounds__(256) void snn_kernel(
    const double* __restrict__ cur_an, // [B,T,C] fp64 AN currents
    const float* __restrict__ W_b, const float* __restrict__ W_m, const float* __restrict__ W_n,
    const float* __restrict__ W_ic, const float* __restrict__ b_ic,
    const float* __restrict__ W_ac, const float* __restrict__ b_ac,
    float* __restrict__ out)           // [2,B,T,O]
{
    __shared__ __align__(16) double sa[CC + 2*SPW], sbu[CC + 2*SPW],
                                    smu[CC + 2*SPW], snu[CC + 2*SPW];
    __shared__ __align__(16) double sic[CC];
    __shared__ double part[256];
    __shared__ double part2[140];
    __shared__ float wac[OO][CC + 1];     // stride 129 f32
    __shared__ float outbuf[CHK][2][OO + 1];

    const int b = blockIdx.x;
    const int tid = threadIdx.x;   // 0..255
    const int cb = tid & 127;      // band channel (tid<128 active)

    // ---- band weights -> f32 VGPRs (loaded by all threads; used by tid<128) ----
    float w1f[W1], w2f[W2], w3f[W3];
    #pragma unroll
    for (int x = 0; x < W1; ++x) { int k = cb - R1 + x; w1f[x] = (k >= 0 && k < CC) ? W_b[cb * CC + k] : 0.f; }
    #pragma unroll
    for (int x = 0; x < W2; ++x) { int k = cb - R2 + x; w2f[x] = (k >= 0 && k < CC) ? W_m[cb * CC + k] : 0.f; }
    #pragma unroll
    for (int x = 0; x < W3; ++x) { int k = cb - R3 + x; w3f[x] = (k >= 0 && k < CC) ? W_n[cb * CC + k] : 0.f; }

    // ---- IC weights -> f32 VGPRs: thread = (row r, half h) ----
    const int ric = tid >> 1, hic = tid & 1;
    float wicf[64];
    {
        const float4* src = reinterpret_cast<const float4*>(W_ic + ric * CC + hic * 64);
        #pragma unroll
        for (int k = 0; k < 16; ++k) {
            float4 v = src[k];
            wicf[4*k] = v.x; wicf[4*k+1] = v.y; wicf[4*k+2] = v.z; wicf[4*k+3] = v.w;
        }
    }
    // ---- AC weights -> LDS (row layout, odd stride) ----
    if (tid < 2 * OO) {
        const int r = tid >> 1, h = tid & 1;
        const float4* src = reinterpret_cast<const float4*>(W_ac + r * CC + h * 64);
        #pragma unroll
        for (int k = 0; k < 16; ++k) {
            float4 v = src[k];
            const int base = h * 64 + 4 * k;
            wac[r][base] = v.x; wac[r][base+1] = v.y; wac[r][base+2] = v.z; wac[r][base+3] = v.w;
        }
    }
    if (tid < SPW) {
        sa[tid] = 0.0;  sa[SPW + CC + tid] = 0.0;
        sbu[tid] = 0.0; sbu[SPW + CC + tid] = 0.0;
        smu[tid] = 0.0; smu[SPW + CC + tid] = 0.0;
        snu[tid] = 0.0; snu[SPW + CC + tid] = 0.0;
    }
    const double bic = (tid < CC) ? (double)b_ic[tid] : 0.0;
    const double bac = (tid < OO) ? (double)b_ac[tid] : 0.0;
    __syncthreads();

    double m1 = 0, m2 = 0, m3 = 0, m4 = 0, m5 = 0, mac = 0;

    for (int tc = 0; tc < TT; tc += CHK) {
        double curb[CHK];
        if (tid < CC) {
            #pragma unroll
            for (int k = 0; k < CHK; ++k)
                curb[k] = cur_an[(b * TT + tc + k) * CC + tid];
        }
        #pragma unroll
        for (int u = 0; u < CHK; ++u) {
            // ---- AN (th 0.5) ----
            if (tid < CC) {
                double mem = 0.9 * m1 + curb[u];
                double d = mem - 0.5; bool s = d > 0.0; m1 = s ? d : mem;
                sa[SPW + tid] = s ? 1.0 : 0.0;
            }
            __syncthreads();   // bar1
            // ---- Bushy (std=1) ----
            if (tid < CC) {
                const double* sp = &sa[SPW + tid - R1];
                double a0 = 0, a1 = 0, a2 = 0, a3 = 0;
                #pragma unroll
                for (int x = 0; x < W1; x += 4) {
                    a0 = fma((double)w1f[x], sp[x], a0);
                    if (x + 1 < W1) a1 = fma((double)w1f[x + 1], sp[x + 1], a1);
                    if (x + 2 < W1) a2 = fma((double)w1f[x + 2], sp[x + 2], a2);
                    if (x + 3 < W1) a3 = fma((double)w1f[x + 3], sp[x + 3], a3);
                }
                double mem = 0.9 * m2 + ((a0 + a1) + (a2 + a3));
                double d = mem - 1.0; bool s = d > 0.0; m2 = s ? d : mem;
                sbu[SPW + tid] = s ? 1.0 : 0.0;
            }
            __syncthreads();   // bar2
            // ---- Stellate M (std=2) ----
            if (tid < CC) {
                const double* sp = &sbu[SPW + tid - R2];
                double a0 = 0, a1 = 0, a2 = 0, a3 = 0;
                #pragma unroll
                for (int x = 0; x < W2; x += 4) {
                    a0 = fma((double)w2f[x], sp[x], a0);
                    if (x + 1 < W2) a1 = fma((double)w2f[x + 1], sp[x + 1], a1);
                    if (x + 2 < W2) a2 = fma((double)w2f[x + 2], sp[x + 2], a2);
                    if (x + 3 < W2) a3 = fma((double)w2f[x + 3], sp[x + 3], a3);
                }
                double mem = 0.9 * m3 + ((a0 + a1) + (a2 + a3));
                double d = mem - 1.0; bool s = d > 0.0; m3 = s ? d : mem;
                smu[SPW + tid] = s ? 1.0 : 0.0;
            }
            __syncthreads();   // bar3
            // ---- Stellate N (std=3) ----
            if (tid < CC) {
                const double* sp = &smu[SPW + tid - R3];
                double a0 = 0, a1 = 0, a2 = 0, a3 = 0;
                #pragma unroll
                for (int x = 0; x < W3; x += 4) {
                    a0 = fma((double)w3f[x], sp[x], a0);
                    if (x + 1 < W3) a1 = fma((double)w3f[x + 1], sp[x + 1], a1);
                    if (x + 2 < W3) a2 = fma((double)w3f[x + 2], sp[x + 2], a2);
                    if (x + 3 < W3) a3 = fma((double)w3f[x + 3], sp[x + 3], a3);
                }
                double mem = 0.9 * m4 + ((a0 + a1) + (a2 + a3));
                double d = mem - 1.0; bool s = d > 0.0; m4 = s ? d : mem;
                snu[SPW + tid] = s ? 1.0 : 0.0;
            }
            __syncthreads();   // bar4
            // ---- IC dense 128x128: all 256 threads, weights in VGPR ----
            {
                const double* sp = &snu[SPW + hic * 64];
                double a0 = 0, a1 = 0, a2 = 0, a3 = 0;
                #pragma unroll
                for (int k = 0; k < 64; k += 4) {
                    double2 sv0 = *reinterpret_cast<const double2*>(&sp[k]);
                    double2 sv1 = *reinterpret_cast<const double2*>(&sp[k + 2]);
                    a0 = fma((double)wicf[k],     sv0.x, a0);
                    a1 = fma((double)wicf[k + 1], sv0.y, a1);
                    a2 = fma((double)wicf[k + 2], sv1.x, a2);
                    a3 = fma((double)wicf[k + 3], sv1.y, a3);
                }
                part[tid] = (a0 + a1) + (a2 + a3);
            }
            __syncthreads();   // bar5
            if (tid < CC) {
                double acc = part[2 * tid] + part[2 * tid + 1] + bic;
                double mem = 0.9 * m5 + acc;
                double d = mem - 1.0; bool s = d > 0.0; m5 = s ? d : mem;
                sic[tid] = s ? 1.0 : 0.0;
            }
            __syncthreads();   // bar6
            // ---- AC 35x128: 4 threads/row, weights from LDS (odd stride) ----
            if (tid < 4 * OO) {
                const int q = tid / OO, o = tid - q * OO;
                const float* wr = &wac[o][q * 32];
                const double* sp = &sic[q * 32];
                double a0 = 0, a1 = 0;
                #pragma unroll
                for (int k = 0; k < 32; k += 2) {
                    double2 sv = *reinterpret_cast<const double2*>(&sp[k]);
                    a0 = fma((double)wr[k],     sv.x, a0);
                    a1 = fma((double)wr[k + 1], sv.y, a1);
                }
                part2[tid] = a0 + a1;
            }
            __syncthreads();   // bar7
            if (tid < OO) {
                double acc = ((part2[tid] + part2[tid + OO]) +
                              (part2[tid + 2 * OO] + part2[tid + 3 * OO])) + bac;
                double mem = 0.9 * mac + acc;
                double d = mem - 1.0; bool s = d > 0.0;
                mac = s ? d : mem;
                outbuf[u][0][tid] = s ? 1.f : 0.f;
                outbuf[u][1][tid] = (float)mac;
            }
        }
        __syncthreads();       // bar8: outbuf complete
        for (int i = tid; i < CHK * 2 * OO; i += 256) {
            const int k = i / (2 * OO);
            const int r = i - k * 2 * OO;
            const int which = r / OO;
            const int o = r - which * OO;
            const int idx = (b * TT + tc + k) * OO + o;
            out[which ? (BTO + idx) : idx] = outbuf[k][which][o];
        }
    }
}

extern "C" void kernel_launch(void* const* d_in, const int* in_sizes, int n_in,
                              void* d_out, int out_size, void* d_ws, size_t ws_size,
                              hipStream_t stream) {
    const float* audio = (const float*)d_in[0];
    const float* W_an  = (const float*)d_in[2];
    const float* b_an  = (const float*)d_in[3];
    const float* W_b   = (const float*)d_in[4];
    const float* W_m   = (const float*)d_in[5];
    const float* W_n   = (const float*)d_in[6];
    const float* W_ic  = (const float*)d_in[7];
    const float* b_ic  = (const float*)d_in[8];
    const float* W_ac  = (const float*)d_in[9];
    const float* b_ac  = (const float*)d_in[10];
    // d_in[1] = gt_kernels (rebuilt analytically), d_in[11] = ihc_win (160)

    char* ws = (char*)d_ws;
    double* Wt    = (double*)(ws + WT_OFF);
    double* par   = (double*)(ws + PAR_OFF);
    double* cur_d = (double*)(ws + CUR_OFF);
    float*  xt    = (float*)(ws + XT_OFF);
    float*  out   = (float*)d_out;

    gt_tables<<<dim3(CC), dim3(512), 0, stream>>>(Wt, par);
    conv_rec<<<dim3(BB * NSEG), dim3(128), 0, stream>>>(audio, Wt, par, xt);
    an_cur_kernel<<<dim3(BB * TT), dim3(128), 0, stream>>>(xt, W_an, b_an, cur_d);
    snn_kernel<<<dim3(BB), dim3(256), 0, stream>>>(
        cur_d, W_b, W_m, W_n, W_ic, b_ic, W_ac, b_ac, out);
}

// Round 9
// 531.530 us; speedup vs baseline: 1.4625x; 1.0805x over previous
//
#include <hip/hip_runtime.h>
#include <math.h>

#define BB 32
#define NN 16000
#define CC 128
#define LL 512
#define OO 35
#define TT 100
#define BTO (BB * TT * OO)   // 112000
#define FSR 16000.0

// conv recursion segmentation
#define SEG 640              // 4 IHC windows per segment
#define NSEG 25
#define SPAN 1153            // audio span per segment: [n0-256, n0+896]

// ws layout (bytes). cur_d overlaps Wt/params (dead by the time an_cur runs).
#define WT_OFF   0            // [512][128][2] double = 1 MB
#define PAR_OFF  0x100000     // [128][16] double = 16 KB
#define CUR_OFF  0            // [3200][128] double = 3.28 MB (written after conv)
#define XT_OFF   0x350000     // [3200][128] float = 1.64 MB

// ---------------- Gammatone tables: Wt[l][c] = rho_c^l, per-channel params ----------------
__global__ __launch_bounds__(512) void gt_tables(double* __restrict__ Wt,
                                                 double* __restrict__ par) {
    const int c = blockIdx.x;      // 0..127
    const int l = threadIdx.x;     // 0..511
    const double TWO_PI = 6.283185307179586476925287;
    const double e_lo = 21.4 * log10(4.37 * 100.0 / 1000.0 + 1.0);
    const double e_hi = 21.4 * log10(4.37 * 8000.0 / 1000.0 + 1.0);
    const double step = (e_hi - e_lo) / 127.0;
    const double e = (c == 127) ? e_hi : e_lo + c * step;
    const double cf = (pow(10.0, e / 21.4) - 1.0) * 1000.0 / 4.37;
    const double bw = 1.019 * 24.7 * (4.37 * cf / 1000.0 + 1.0);

    const double t = (double)l / FSR;
    const double env = exp(-TWO_PI * bw * t);
    const double ang = TWO_PI * cf * t;
    const double wr = env * cos(ang);
    const double wi = env * sin(ang);
    Wt[(l * CC + c) * 2 + 0] = wr;
    Wt[(l * CC + c) * 2 + 1] = wi;

    __shared__ double red[512];
    const double l3 = (double)l * (double)l * (double)l;
    const double q = l3 * wr;
    red[l] = q * q;
    __syncthreads();
    for (int s = 256; s > 0; s >>= 1) {
        if (l < s) red[l] += red[l + s];
        __syncthreads();
    }
    if (l == 0) {
        double* p = par + c * 16;
        const double a1 = TWO_PI * bw / FSR, th1 = TWO_PI * cf / FSR;
        const double e1 = exp(-a1);
        p[0] = e1 * cos(th1);              // rho.re
        p[1] = e1 * sin(th1);              // rho.im
        const double aL = TWO_PI * bw * (512.0 / FSR), thL = TWO_PI * cf * (512.0 / FSR);
        const double eL = exp(-aL);
        const double pr = eL * cos(thL), pim = eL * sin(thL);   // rho^512
        p[2] = pr;              p[3] = pim;               // C0
        p[4] = 512.0 * pr;      p[5] = 512.0 * pim;       // C1
        p[6] = 130816.0 * pr;   p[7] = 130816.0 * pim;    // C2
        p[8] = 22238720.0 * pr; p[9] = 22238720.0 * pim;  // C3
        p[10] = 1.0 / sqrt(red[0]);
    }
}

// ---------------- Conv via exact FIR recursion + ReLU + IHC window mean ----------------
__global__ __launch_bounds__(128) void conv_rec(
    const float* __restrict__ audio,   // [B,N]
    const double* __restrict__ Wt,     // [512][128][2]
    const double* __restrict__ par,    // [128][16]
    float* __restrict__ xt)            // [B,T,C]
{
    const int blk = blockIdx.x;
    const int b = blk / NSEG;
    const int seg = blk % NSEG;
    const int n0 = seg * SEG;
    const int c = threadIdx.x;

    __shared__ float alds[SPAN];
    for (int i = c; i < SPAN; i += 128) {
        const int g = n0 - 256 + i;
        alds[i] = (g >= 0 && g < NN) ? audio[b * NN + g] : 0.0f;
    }
    __syncthreads();

    const double* p = par + c * 16;
    const double rr = p[0], ri = p[1];
    const double cr0 = p[2], ci0 = p[3], cr1 = p[4], ci1 = p[5];
    const double cr2 = p[6], ci2 = p[7], cr3 = p[8], ci3 = p[9];
    const double scale = p[10];

    double d0r = 0, d0i = 0, d1r = 0, d1i = 0, d2r = 0, d2i = 0, d3r = 0, d3i = 0;
    #pragma unroll 4
    for (int l = 0; l < 512; ++l) {
        const double wr = Wt[(l * CC + c) * 2 + 0];
        const double wi = Wt[(l * CC + c) * 2 + 1];
        const double av = (double)alds[SEG + 1 + l];
        const double bl = (double)l;
        const double b2 = bl * (bl - 1.0) * 0.5;
        const double b3 = b2 * (bl - 2.0) * (1.0 / 3.0);
        d0r = fma(wr, av, d0r);              d0i = fma(wi, av, d0i);
        const double t1 = av * bl;
        d1r = fma(wr, t1, d1r);              d1i = fma(wi, t1, d1i);
        const double t2 = av * b2;
        d2r = fma(wr, t2, d2r);              d2i = fma(wi, t2, d2i);
        const double t3 = av * b3;
        d3r = fma(wr, t3, d3r);              d3i = fma(wi, t3, d3i);
    }

    double wsum = 0.0;
    int widx = (b * TT + seg * 4 + 3) * CC + c;
    int cnt = 0;
    #pragma unroll 2
    for (int m = 0; m < SEG; ++m) {
        const int li = SEG - m;
        const double ain  = (double)alds[li];
        const double aout = (double)alds[li + 512];
        const double t3r = d3r + d2r, t3i = d3i + d2i;
        const double t2r = d2r + d1r, t2i = d2i + d1i;
        const double t1r = d1r + d0r, t1i = d1i + d0i;
        d3r = fma(t3r, rr, fma(t3i, -ri, -cr3 * aout));
        d3i = fma(t3r, ri, fma(t3i,  rr, -ci3 * aout));
        d2r = fma(t2r, rr, fma(t2i, -ri, -cr2 * aout));
        d2i = fma(t2r, ri, fma(t2i,  rr, -ci2 * aout));
        d1r = fma(t1r, rr, fma(t1i, -ri, -cr1 * aout));
        d1i = fma(t1r, ri, fma(t1i,  rr, -ci1 * aout));
        const double o0r = fma(d0r, rr, fma(d0i, -ri, fma(-cr0, aout, ain)));
        const double o0i = fma(d0r, ri, fma(d0i,  rr, -ci0 * aout));
        d0r = o0r; d0i = o0i;
        const double yv = scale * fma(6.0, d2r + d3r, d1r);
        float yf = (float)yv;
        yf = yf > 0.0f ? yf : 0.0f;
        wsum += (double)yf;
        if (++cnt == 160) {
            xt[widx] = (float)(wsum / 160.0);
            widx -= CC;
            wsum = 0.0;
            cnt = 0;
        }
    }
}

// ---------------- AN current precompute (fp64): cur = xt @ W_an^T + b_an ----------------
__global__ __launch_bounds__(128) void an_cur_kernel(
    const float* __restrict__ xt, const float* __restrict__ W_an,
    const float* __restrict__ b_an, double* __restrict__ cur_d)
{
    __shared__ float xr[CC];
    const int row = blockIdx.x;          // b*T + t
    const int c = threadIdx.x;
    xr[c] = xt[row * CC + c];
    __syncthreads();
    const float* wr = W_an + c * CC;
    double acc = (double)b_an[c];
    #pragma unroll
    for (int k = 0; k < CC; k += 4) {
        float4 w4 = *reinterpret_cast<const float4*>(wr + k);
        acc += (double)w4.x * (double)xr[k]
             + (double)w4.y * (double)xr[k+1]
             + (double)w4.z * (double)xr[k+2]
             + (double)w4.w * (double)xr[k+3];
    }
    cur_d[row * CC + c] = acc;
}

// ---------------- SNN scan: SYSTOLIC PIPELINE, 10 waves (640 thr) per batch ----------------
// Stage->wave map (stage offset in ticks): AN=0(W0), B=1(W1), M=2(W2), N=3(W3),
// ICpart=4(W4-7, 32 taps each), ICcomb=5(W8), ACpart=6(W9 rows0-31 + W0 lanes0-5
// rows32-34), ACcomb+store=7(W8). One __syncthreads per tick; buffers double-
// buffered by t&1 (rewrite distance 2 ticks). fp64 math throughout.
#define R1 8
#define W1 17
#define R2 16
#define W2 33
#define R3 24
#define W3 49
#define SPW 24               // pad each side of band spike rows (row len 176)

__global__ __launch_bounds__(640) void snn_kernel(
    const double* __restrict__ cur_an, // [B,T,C] fp64 AN currents
    const float* __restrict__ W_b, const float* __restrict__ W_m, const float* __restrict__ W_n,
    const float* __restrict__ W_ic, const float* __restrict__ b_ic,
    const float* __restrict__ W_ac, const float* __restrict__ b_ac,
    float* __restrict__ out)           // [2,B,T,O]
{
    __shared__ __align__(16) double sa[2][176], sb[2][176], sm[2][176];
    __shared__ __align__(16) double sn_[2][CC];
    __shared__ __align__(16) double icp[2][4][CC];
    __shared__ __align__(16) double sic[2][CC];
    __shared__ double acp[2][2][36];

    const int b = blockIdx.x;
    const int tid = threadIdx.x;   // 0..639
    const int wid = tid >> 6;      // 0..9
    const int l = tid & 63;

    // zero band spike rows (pads must be 0; data region overwritten before read)
    {
        double* z0 = &sa[0][0]; double* z1 = &sb[0][0]; double* z2 = &sm[0][0];
        for (int i = tid; i < 352; i += 640) { z0[i] = 0.0; z1[i] = 0.0; z2[i] = 0.0; }
    }

    // ---- role-dependent weights in a shared register array (static indexing) ----
    float wreg[2 * W3];                       // max: N wave, 98 f32
    double bic0 = 0.0, bic1 = 0.0, bacv = 0.0;
    double mm0 = 0.0, mm1 = 0.0, macv = 0.0;  // per-wave membranes
    double2 pf0 = make_double2(0.0, 0.0), pf1 = make_double2(0.0, 0.0);

    const int c0 = 2 * l, c1 = 2 * l + 1;
    if (wid == 0) {
        pf0 = *reinterpret_cast<const double2*>(&cur_an[(b * TT + 0) * CC + c0]);
        pf1 = *reinterpret_cast<const double2*>(&cur_an[(b * TT + 1) * CC + c0]);
        if (l < 6) {                           // AC rows 32-34 halves
            const int r = 32 + (l >> 1), h = l & 1;
            #pragma unroll
            for (int j = 0; j < 64; ++j) wreg[j] = W_ac[r * CC + 64 * h + j];
        }
    } else if (wid == 1) {
        #pragma unroll
        for (int x = 0; x < W1; ++x) {
            int k0 = c0 - R1 + x, k1 = c1 - R1 + x;
            wreg[x]      = (k0 >= 0 && k0 < CC) ? W_b[c0 * CC + k0] : 0.f;
            wreg[W1 + x] = (k1 >= 0 && k1 < CC) ? W_b[c1 * CC + k1] : 0.f;
        }
    } else if (wid == 2) {
        #pragma unroll
        for (int x = 0; x < W2; ++x) {
            int k0 = c0 - R2 + x, k1 = c1 - R2 + x;
            wreg[x]      = (k0 >= 0 && k0 < CC) ? W_m[c0 * CC + k0] : 0.f;
            wreg[W2 + x] = (k1 >= 0 && k1 < CC) ? W_m[c1 * CC + k1] : 0.f;
        }
    } else if (wid == 3) {
        #pragma unroll
        for (int x = 0; x < W3; ++x) {
            int k0 = c0 - R3 + x, k1 = c1 - R3 + x;
            wreg[x]      = (k0 >= 0 && k0 < CC) ? W_n[c0 * CC + k0] : 0.f;
            wreg[W3 + x] = (k1 >= 0 && k1 < CC) ? W_n[c1 * CC + k1] : 0.f;
        }
    } else if (wid <= 7) {
        const int q = wid - 4;
        #pragma unroll
        for (int j = 0; j < 32; ++j) {
            wreg[j]      = W_ic[c0 * CC + 32 * q + j];
            wreg[32 + j] = W_ic[c1 * CC + 32 * q + j];
        }
    } else if (wid == 8) {
        bic0 = (double)b_ic[c0]; bic1 = (double)b_ic[c1];
        if (l < OO) bacv = (double)b_ac[l];
    } else { // wid == 9: AC rows 0-31
        const int r = l >> 1, h = l & 1;
        #pragma unroll
        for (int j = 0; j < 64; ++j) wreg[j] = W_ac[r * CC + 64 * h + j];
    }
    __syncthreads();

    for (int tick = 0; tick < TT + 7; ++tick) {
        if (wid == 0) {
            const int t = tick;
            if (t < TT) {
                double2 cv = pf0; pf0 = pf1;
                if (t + 2 < TT)
                    pf1 = *reinterpret_cast<const double2*>(&cur_an[(b * TT + t + 2) * CC + c0]);
                double me0 = 0.9 * mm0 + cv.x; double d0 = me0 - 0.5;
                bool s0 = d0 > 0.0; mm0 = s0 ? d0 : me0;
                double me1 = 0.9 * mm1 + cv.y; double d1 = me1 - 0.5;
                bool s1 = d1 > 0.0; mm1 = s1 ? d1 : me1;
                *reinterpret_cast<double2*>(&sa[t & 1][SPW + c0]) =
                    make_double2(s0 ? 1.0 : 0.0, s1 ? 1.0 : 0.0);
            }
            const int t6 = tick - 6;
            if (l < 6 && t6 >= 0 && t6 < TT) {
                const int p = t6 & 1, h = l & 1;
                const double* sp = &sic[p][h * 64];
                double a0 = 0, a1 = 0, a2 = 0, a3 = 0;
                #pragma unroll
                for (int k = 0; k < 64; k += 4) {
                    double2 v0 = *reinterpret_cast<const double2*>(&sp[k]);
                    double2 v1 = *reinterpret_cast<const double2*>(&sp[k + 2]);
                    a0 = fma((double)wreg[k],     v0.x, a0);
                    a1 = fma((double)wreg[k + 1], v0.y, a1);
                    a2 = fma((double)wreg[k + 2], v1.x, a2);
                    a3 = fma((double)wreg[k + 3], v1.y, a3);
                }
                acp[p][h][32 + (l >> 1)] = (a0 + a1) + (a2 + a3);
            }
        } else if (wid == 1) {
            const int t = tick - 1;
            if (t >= 0 && t < TT) {
                const int p = t & 1;
                const double2* pw = reinterpret_cast<const double2*>(&sa[p][SPW + c0 - R1]);
                double aA0 = 0, aA1 = 0, aB0 = 0, aB1 = 0;
                #pragma unroll
                for (int i = 0; i < 9; ++i) {       // window vals wv[2i],wv[2i+1]
                    double2 v = pw[i];
                    if (2 * i < W1)     aA0 = fma((double)wreg[2 * i],          v.x, aA0);
                    if (2 * i + 1 < W1) aA1 = fma((double)wreg[2 * i + 1],      v.y, aA1);
                    if (2 * i >= 1)     aB0 = fma((double)wreg[W1 + 2 * i - 1], v.x, aB0);
                    if (2 * i < W1)     aB1 = fma((double)wreg[W1 + 2 * i],     v.y, aB1);
                }
                double me0 = 0.9 * mm0 + (aA0 + aA1); double d0 = me0 - 1.0;
                bool s0 = d0 > 0.0; mm0 = s0 ? d0 : me0;
                double me1 = 0.9 * mm1 + (aB0 + aB1); double d1 = me1 - 1.0;
                bool s1 = d1 > 0.0; mm1 = s1 ? d1 : me1;
                *reinterpret_cast<double2*>(&sb[p][SPW + c0]) =
                    make_double2(s0 ? 1.0 : 0.0, s1 ? 1.0 : 0.0);
            }
        } else if (wid == 2) {
            const int t = tick - 2;
            if (t >= 0 && t < TT) {
                const int p = t & 1;
                const double2* pw = reinterpret_cast<const double2*>(&sb[p][SPW + c0 - R2]);
                double aA0 = 0, aA1 = 0, aB0 = 0, aB1 = 0;
                #pragma unroll
                for (int i = 0; i < 17; ++i) {
                    double2 v = pw[i];
                    if (2 * i < W2)     aA0 = fma((double)wreg[2 * i],          v.x, aA0);
                    if (2 * i + 1 < W2) aA1 = fma((double)wreg[2 * i + 1],      v.y, aA1);
                    if (2 * i >= 1)     aB0 = fma((double)wreg[W2 + 2 * i - 1], v.x, aB0);
                    if (2 * i < W2)     aB1 = fma((double)wreg[W2 + 2 * i],     v.y, aB1);
                }
                double me0 = 0.9 * mm0 + (aA0 + aA1); double d0 = me0 - 1.0;
                bool s0 = d0 > 0.0; mm0 = s0 ? d0 : me0;
                double me1 = 0.9 * mm1 + (aB0 + aB1); double d1 = me1 - 1.0;
                bool s1 = d1 > 0.0; mm1 = s1 ? d1 : me1;
                *reinterpret_cast<double2*>(&sm[p][SPW + c0]) =
                    make_double2(s0 ? 1.0 : 0.0, s1 ? 1.0 : 0.0);
            }
        } else if (wid == 3) {
            const int t = tick - 3;
            if (t >= 0 && t < TT) {
                const int p = t & 1;
                const double2* pw = reinterpret_cast<const double2*>(&sm[p][SPW + c0 - R3]);
                double aA0 = 0, aA1 = 0, aB0 = 0, aB1 = 0;
                #pragma unroll
                for (int i = 0; i < 25; ++i) {
                    double2 v = pw[i];
                    if (2 * i < W3)     aA0 = fma((double)wreg[2 * i],          v.x, aA0);
                    if (2 * i + 1 < W3) aA1 = fma((double)wreg[2 * i + 1],      v.y, aA1);
                    if (2 * i >= 1)     aB0 = fma((double)wreg[W3 + 2 * i - 1], v.x, aB0);
                    if (2 * i < W3)     aB1 = fma((double)wreg[W3 + 2 * i],     v.y, aB1);
                }
                double me0 = 0.9 * mm0 + (aA0 + aA1); double d0 = me0 - 1.0;
                bool s0 = d0 > 0.0; mm0 = s0 ? d0 : me0;
                double me1 = 0.9 * mm1 + (aB0 + aB1); double d1 = me1 - 1.0;
                bool s1 = d1 > 0.0; mm1 = s1 ? d1 : me1;
                *reinterpret_cast<double2*>(&sn_[p][c0]) =
                    make_double2(s0 ? 1.0 : 0.0, s1 ? 1.0 : 0.0);
            }
        } else if (wid <= 7) {
            const int t = tick - 4;
            if (t >= 0 && t < TT) {
                const int p = t & 1, q = wid - 4;
                const double* sp = &sn_[p][32 * q];       // wave-uniform broadcast
                double a0 = 0, a1 = 0, g0 = 0, g1 = 0;
                #pragma unroll
                for (int k = 0; k < 32; k += 2) {
                    double2 v = *reinterpret_cast<const double2*>(&sp[k]);
                    a0 = fma((double)wreg[k],          v.x, a0);
                    a1 = fma((double)wreg[k + 1],      v.y, a1);
                    g0 = fma((double)wreg[32 + k],     v.x, g0);
                    g1 = fma((double)wreg[32 + k + 1], v.y, g1);
                }
                *reinterpret_cast<double2*>(&icp[p][q][c0]) =
                    make_double2(a0 + a1, g0 + g1);
            }
        } else if (wid == 8) {
            const int t = tick - 5;
            if (t >= 0 && t < TT) {
                const int p = t & 1;
                double2 q0 = *reinterpret_cast<const double2*>(&icp[p][0][c0]);
                double2 q1 = *reinterpret_cast<const double2*>(&icp[p][1][c0]);
                double2 q2 = *reinterpret_cast<const double2*>(&icp[p][2][c0]);
                double2 q3 = *reinterpret_cast<const double2*>(&icp[p][3][c0]);
                double acc0 = ((q0.x + q1.x) + (q2.x + q3.x)) + bic0;
                double acc1 = ((q0.y + q1.y) + (q2.y + q3.y)) + bic1;
                double me0 = 0.9 * mm0 + acc0; double d0 = me0 - 1.0;
                bool s0 = d0 > 0.0; mm0 = s0 ? d0 : me0;
                double me1 = 0.9 * mm1 + acc1; double d1 = me1 - 1.0;
                bool s1 = d1 > 0.0; mm1 = s1 ? d1 : me1;
                *reinterpret_cast<double2*>(&sic[p][c0]) =
                    make_double2(s0 ? 1.0 : 0.0, s1 ? 1.0 : 0.0);
            }
            const int t7 = tick - 7;
            if (l < OO && t7 >= 0 && t7 < TT) {
                const int p = t7 & 1;
                double acc = (acp[p][0][l] + acp[p][1][l]) + bacv;
                double mem = 0.9 * macv + acc;
                double d = mem - 1.0; bool s = d > 0.0;
                macv = s ? d : mem;
                const int idx = (b * TT + t7) * OO + l;
                out[idx] = s ? 1.f : 0.f;
                out[BTO + idx] = (float)macv;
            }
        } else { // wid == 9: AC rows 0-31
            const int t = tick - 6;
            if (t >= 0 && t < TT) {
                const int p = t & 1, r = l >> 1, h = l & 1;
                const double* sp = &sic[p][h * 64];
                double a0 = 0, a1 = 0, a2 = 0, a3 = 0;
                #pragma unroll
                for (int k = 0; k < 64; k += 4) {
                    double2 v0 = *reinterpret_cast<const double2*>(&sp[k]);
                    double2 v1 = *reinterpret_cast<const double2*>(&sp[k + 2]);
                    a0 = fma((double)wreg[k],     v0.x, a0);
                    a1 = fma((double)wreg[k + 1], v0.y, a1);
                    a2 = fma((double)wreg[k + 2], v1.x, a2);
                    a3 = fma((double)wreg[k + 3], v1.y, a3);
                }
                acp[p][h][r] = (a0 + a1) + (a2 + a3);
            }
        }
        __syncthreads();
    }
}

extern "C" void kernel_launch(void* const* d_in, const int* in_sizes, int n_in,
                              void* d_out, int out_size, void* d_ws, size_t ws_size,
                              hipStream_t stream) {
    const float* audio = (const float*)d_in[0];
    const float* W_an  = (const float*)d_in[2];
    const float* b_an  = (const float*)d_in[3];
    const float* W_b   = (const float*)d_in[4];
    const float* W_m   = (const float*)d_in[5];
    const float* W_n   = (const float*)d_in[6];
    const float* W_ic  = (const float*)d_in[7];
    const float* b_ic  = (const float*)d_in[8];
    const float* W_ac  = (const float*)d_in[9];
    const float* b_ac  = (const float*)d_in[10];
    // d_in[1] = gt_kernels (rebuilt analytically), d_in[11] = ihc_win (160)

    char* ws = (char*)d_ws;
    double* Wt    = (double*)(ws + WT_OFF);
    double* par   = (double*)(ws + PAR_OFF);
    double* cur_d = (double*)(ws + CUR_OFF);
    float*  xt    = (float*)(ws + XT_OFF);
    float*  out   = (float*)d_out;

    gt_tables<<<dim3(CC), dim3(512), 0, stream>>>(Wt, par);
    conv_rec<<<dim3(BB * NSEG), dim3(128), 0, stream>>>(audio, Wt, par, xt);
    an_cur_kernel<<<dim3(BB * TT), dim3(128), 0, stream>>>(xt, W_an, b_an, cur_d);
    snn_kernel<<<dim3(BB), dim3(640), 0, stream>>>(
        cur_d, W_b, W_m, W_n, W_ic, b_ic, W_ac, b_ac, out);
}